// Round 7
// baseline (790.310 us; speedup 1.0000x reference)
//
#include <hip/hip_runtime.h>
#include <hip/hip_bf16.h>
#include <utility>

// ---------------------------------------------------------------------------
// BatteriesInteractionBlock: equivariant tensor-product message passing.
//   N=10000 nodes, E=160000 edges, C=32 channels, 16 irreps (L_MAX=3),
//   34 CG paths, scatter-sum over dst, then 512x512 linear. Output f32.
//
// Round-7 (from r6 counters: 50% unexplained stalls, occupancy 45%):
//   - 7 blocks/CU: LDS 37.4 -> 22.7KB (half-tile flush, B2s gone, ssrc gone)
//   - B-comp fully in-register per lane (no LDS round-trip on critical path);
//     cg table re-laid out with 16B-aligned row strides {2,4,8,8} -> f32x4
//   - DIAGNOSTIC: edge_kernel<1> (no B-comp) and <2> (no a-comp) launched
//     full-grid before the accb memset (outputs wiped; timing visible in the
//     per-dispatch profile). One-time headline cost to get phase marginals.
// ---------------------------------------------------------------------------

#define NPATH 34
#define TOTCGF 4652

typedef __attribute__((ext_vector_type(2))) float f32x2;
typedef __attribute__((ext_vector_type(4))) float f32x4;
typedef __attribute__((ext_vector_type(4))) unsigned u32x4;
typedef __attribute__((ext_vector_type(8))) short short8;

// path tables: (l1,l2,l3) in reference order (sorted by l1)
constexpr int PL1[NPATH] = {0,0,0,0, 1,1,1,1,1,1,1,1,1, 2,2,2,2,2,2,2,2,2,2,2, 3,3,3,3,3,3,3,3,3,3};
constexpr int PL2[NPATH] = {0,1,2,3, 0,1,1,1,2,2,2,3,3, 0,1,1,1,2,2,2,2,3,3,3, 0,1,1,2,2,2,3,3,3,3};
constexpr int PL3[NPATH] = {0,1,2,3, 1,0,1,2,1,2,3,2,3, 2,1,2,3,0,1,2,3,1,2,3, 3,2,3,1,2,3,0,1,2,3};
// 16B-aligned cg starts; per-path row stride RS(l1) = {2,4,8,8}; layout
// [k][j][i(pad to RS)], slot = PCGF[p] + (k*S2 + j)*RS + i
constexpr int PCGF[NPATH] = {0,4,24,76, 176,188,200,236,296,356,456,596,736,
                             932,972,1044,1164,1332,1372,1492,1692,1972,2140,2420,
                             2812,2868,2988,3156,3276,3476,3756,3812,3980,4260};
// i-pair slot offsets per l1 block in x2s (widths {1,2,3,4}, 10 total)
constexpr int PO1A[4] = {0, 1, 3, 6};

__device__ __forceinline__ short f2bf(float f){
  unsigned u = __float_as_uint(f);
  unsigned r = (u + 0x7fffu + ((u >> 16) & 1u)) >> 16;
  return (short)r;
}

// ---- packed-math helpers (VOP3P asm verified on-device rounds 3-6) --------
__device__ __forceinline__ f32x2 pk_fma(f32x2 a, f32x2 x, f32x2 b){
  asm("v_pk_fma_f32 %0, %1, %2, %0" : "+v"(a) : "v"(x), "v"(b));
  return a;
}
__device__ __forceinline__ unsigned cvt_pk_bf16(float lo, float hi){
  unsigned r;
  asm("v_cvt_pk_bf16_f32 %0, %1, %2" : "=v"(r) : "v"(lo), "v"(hi));
  return r;
}
// c += a.lo*b.lo + a.hi*b.hi   (2x bf16 FMA, f32 accumulate)
__device__ __forceinline__ float dot2bf(unsigned a, unsigned b, float c){
  asm("v_dot2_f32_bf16 %0, %1, %2, %0" : "+v"(c) : "v"(a), "v"(b));
  return c;
}

// ------------------------------ prep_cgf -----------------------------------
__device__ double factd(int n){
  double f = 1.0;
  for (int i = 2; i <= n; i++) f *= (double)i;
  return f;
}

__device__ double cg_complex(int j1,int m1,int j2,int m2,int j3,int m3){
  if (m1 + m2 != m3) return 0.0;
  int dj = j1 - j2; if (dj < 0) dj = -dj;
  if (j3 < dj || j3 > j1 + j2) return 0.0;
  double pre = sqrt((double)(2*j3+1) * factd(j3+j1-j2) * factd(j3-j1+j2) *
                    factd(j1+j2-j3) / factd(j1+j2+j3+1));
  pre *= sqrt(factd(j3+m3)*factd(j3-m3)*factd(j1-m1)*factd(j1+m1)*
              factd(j2-m2)*factd(j2+m2));
  int k0 = 0;
  if (j2-j3-m1 > k0) k0 = j2-j3-m1;
  if (j1+m2-j3 > k0) k0 = j1+m2-j3;
  int k1 = j1+j2-j3;
  if (j1-m1 < k1) k1 = j1-m1;
  if (j2+m2 < k1) k1 = j2+m2;
  double s = 0.0;
  for (int k = k0; k <= k1; k++){
    double d = factd(k)*factd(j1+j2-j3-k)*factd(j1-m1-k)*factd(j2+m2-k)*
               factd(j3-j2+m1+k)*factd(j3-j1-m2+k);
    s += ((k & 1) ? -1.0 : 1.0) / d;
  }
  return pre * s;
}

struct Uent { int m; double re, im; };

__device__ int urow(int l, int a, Uent* o){
  const double s2 = 0.70710678118654752440;
  int ra = a - l;
  if (ra == 0){ o[0] = {0, 1.0, 0.0}; return 1; }
  if (ra > 0){
    int m = ra;
    o[0] = { -m, s2, 0.0 };
    o[1] = {  m, (m & 1) ? -s2 : s2, 0.0 };
    return 2;
  }
  int m = -ra;
  o[0] = { -m, 0.0, s2 };
  o[1] = {  m, 0.0, (m & 1) ? s2 : -s2 };
  return 2;
}

__device__ float real_cg(int l1, int l2, int l3, int i, int j, int k){
  Uent u1[2], u2[2], u3[2];
  int n1 = urow(l1, i, u1), n2 = urow(l2, j, u2), n3 = urow(l3, k, u3);
  double sre = 0.0, sim = 0.0;
  for (int a = 0; a < n1; a++)
    for (int b = 0; b < n2; b++)
      for (int c = 0; c < n3; c++){
        double cr = u1[a].re*u2[b].re - u1[a].im*u2[b].im;
        double ci = u1[a].re*u2[b].im + u1[a].im*u2[b].re;
        double tr = cr*u3[c].re + ci*u3[c].im;   // times conj(u3)
        double ti = ci*u3[c].re - cr*u3[c].im;
        double cgv = cg_complex(l1, u1[a].m, l2, u2[b].m, l3, u3[c].m);
        sre += tr*cgv; sim += ti*cgv;
      }
  return (float)((((l1+l2+l3) & 1) == 0) ? sre : sim);
}

__global__ void prep_cgf(float* __restrict__ cgf){
  int idx = blockIdx.x * blockDim.x + threadIdx.x;
  if (idx >= TOTCGF) return;
  int p = 0;
  for (int q = 1; q < NPATH; q++) if (idx >= PCGF[q]) p = q;
  const int l1 = PL1[p], l2 = PL2[p], l3 = PL3[p];
  const int S1 = 2*l1+1, S2 = 2*l2+1;
  const int RS = (l1 == 0) ? 2 : ((l1 == 1) ? 4 : 8);
  int q  = idx - PCGF[p];
  int kkj = q / RS;
  int ii  = q - kkj*RS;
  float v = 0.f;
  // guard: padding between paths (start alignment) also lands here safely
  if (kkj < (2*l3+1)*S2 && ii < S1){
    int kk = kkj / S2;
    int j  = kkj - kk*S2;
    v = real_cg(l1, l2, l3, ii, j, kk);
  }
  cgf[idx] = v;
}

// ------------------------------ prep_w -------------------------------------
// wt[p][d][c] = bf16(tpw[p][c][d]);  Wb[o][ia] = bf16(W[o][(ia&31)*16 + (ia>>5)])
__global__ void prep_w(const float* __restrict__ tpw, const float* __restrict__ lw,
                       short* __restrict__ wt, short* __restrict__ Wb){
  int idx = blockIdx.x * blockDim.x + threadIdx.x;
  if (idx < NPATH*1024){
    int c = idx & 31, d = (idx >> 5) & 31, p = idx >> 10;
    wt[idx] = f2bf(tpw[(p << 10) + c*32 + d]);
  } else if (idx < NPATH*1024 + 512*512){
    int q = idx - NPATH*1024;
    int o = q >> 9, ia = q & 511;
    Wb[q] = f2bf(lw[o*512 + ((ia & 31) << 4) + (ia >> 5)]);
  }
}

// --------------------------- sort-by-dst prep ------------------------------
__global__ void k_count(const int* __restrict__ ei, int* __restrict__ cnt, int E){
  int e = blockIdx.x*256 + threadIdx.x;
  if (e < E) atomicAdd(&cnt[ei[E + e]], 1);
}

__global__ void k_scan(int* __restrict__ cnt, int N){
  __shared__ int part[256];
  const int t = threadIdx.x;
  const int base = t * 40;
  int loc[40];
  int s = 0;
  #pragma unroll
  for (int q = 0; q < 40; q++){
    int idx = base + q;
    int v = (idx < N) ? cnt[idx] : 0;
    loc[q] = s; s += v;
  }
  part[t] = s;
  __syncthreads();
  for (int d = 1; d < 256; d <<= 1){
    int v = (t >= d) ? part[t - d] : 0;
    __syncthreads();
    part[t] += v;
    __syncthreads();
  }
  int pre = (t == 0) ? 0 : part[t - 1];
  #pragma unroll
  for (int q = 0; q < 40; q++){
    int idx = base + q;
    if (idx < N) cnt[idx] = pre + loc[q];
  }
}

__global__ void k_fill(const int* __restrict__ ei, int* __restrict__ cur,
                       int* __restrict__ perm, int E){
  int e = blockIdx.x*256 + threadIdx.x;
  if (e < E){
    int pos = atomicAdd(&cur[ei[E + e]], 1);
    perm[pos] = e;
  }
}

// --------------------------- path expansion helper -------------------------
template<typename F, size_t... I>
__device__ __forceinline__ void for_each_path(F&& f, std::index_sequence<I...>){
  (f(std::integral_constant<size_t, I>{}), ...);
}

// row swizzle for x2s: bits 2-4 of dword index, keeps b128 alignment
__device__ __forceinline__ int xswz(int r){
  return ((r & 3) << 2) | ((r & 1) << 4);
}

// ------------------------------ edge kernel --------------------------------
// 256 threads (4 waves), 16 dst-sorted edges/block. kg%4==wv wave split.
// V=0 full; V=1 no B-comp (diag); V=2 no a-comp dot2 (diag).
template<int V>
__global__ __launch_bounds__(256, 4) void edge_kernel(
    const float* __restrict__ nf, const int* __restrict__ ei,
    const float* __restrict__ ev, const float* __restrict__ cgfg,
    const short* __restrict__ wt, const int* __restrict__ perm,
    float* __restrict__ accb, int E, int N)
{
  // phase1: x2s[10][16][32] u32 [0,20480) + Ydup f32x2[16][17] [20480,22656)
  // phase2: acc_l[16][256] f32 [0,16384)   (time-disjoint overlay)
  __shared__ __align__(16) char u_lds[22656];
  unsigned* x2s  = (unsigned*)u_lds;
  f32x2*    Yl2  = (f32x2*)(u_lds + 20480);
  float*    acc_l = (float*)u_lds;
  __shared__ int sdst[16];

  const int t    = threadIdx.x;
  const int lane = t & 63;
  const int wv   = t >> 6;
  const int e0   = blockIdx.x * 16;

  // ---- prologue: permuted edge meta + Y (first 16 threads) ----
  if (t < 16){
    int eg = e0 + t;
    int pe = (eg < E) ? perm[eg] : -1;
    float vx = 0.f, vy = 0.f, vz = 0.f; int dn = -1;
    if (pe >= 0){
      vx = ev[pe*3]; vy = ev[pe*3+1]; vz = ev[pe*3+2];
      dn = ei[E + pe];
    }
    float nrm = sqrtf(vx*vx + vy*vy + vz*vz);
    float inv = 1.0f / fmaxf(nrm, 1e-8f);
    float x = vx*inv, y = vy*inv, z = vz*inv;
    float x2 = x*x, y2 = y*y, z2 = z*z;
    float ys[16];
    ys[0]  = 0.28209479177387814f;
    ys[1]  = 0.4886025119029199f * y;
    ys[2]  = 0.4886025119029199f * z;
    ys[3]  = 0.4886025119029199f * x;
    ys[4]  = 1.0925484305920792f * x * y;
    ys[5]  = 1.0925484305920792f * y * z;
    ys[6]  = 0.31539156525252005f * (3.f*z2 - 1.f);
    ys[7]  = 1.0925484305920792f * x * z;
    ys[8]  = 0.5462742152960396f * (x2 - y2);
    ys[9]  = 0.5900435899266435f * y * (3.f*x2 - y2);
    ys[10] = 2.890611442640554f * x * y * z;
    ys[11] = 0.4570457994644658f * y * (5.f*z2 - 1.f);
    ys[12] = 0.3731763325901154f * z * (5.f*z2 - 3.f);
    ys[13] = 0.4570457994644658f * x * (5.f*z2 - 1.f);
    ys[14] = 1.445305721320277f * z * (x2 - y2);
    ys[15] = 0.5900435899266435f * x * (x2 - 3.f*y2);
    #pragma unroll
    for (int j = 0; j < 16; j++) Yl2[t*17 + j] = (f32x2){ys[j], ys[j]};
    sdst[t] = dn;
  }

  // ---- prologue: x gather (once, coalesced) -> packed bf16 pairs in x2s ----
  {
    const int el = t >> 4, c0 = t & 15;
    int eg = e0 + el;
    int pe = (eg < E) ? perm[eg] : -1;
    int s  = (pe >= 0) ? ei[pe] : 0;
    const float* xb = nf + (size_t)s * 512;
    const int sw = xswz(el);
    #pragma unroll
    for (int h = 0; h < 2; h++){
      const int c = c0 + 16*h;
      const float* rp = xb + c * 16;
      f32x4 v0 = ((const f32x4*)rp)[0];
      f32x4 v1 = ((const f32x4*)rp)[1];
      f32x4 v2 = ((const f32x4*)rp)[2];
      f32x4 v3 = ((const f32x4*)rp)[3];
      unsigned d[10];
      d[0] = cvt_pk_bf16(v0[0], 0.f);          // l1=0: (i0, pad)
      d[1] = cvt_pk_bf16(v0[1], v0[2]);        // l1=1: (i1,i2)
      d[2] = cvt_pk_bf16(v0[3], 0.f);          //        (i3, pad)
      d[3] = cvt_pk_bf16(v1[0], v1[1]);        // l1=2: (i4,i5)
      d[4] = cvt_pk_bf16(v1[2], v1[3]);        //        (i6,i7)
      d[5] = cvt_pk_bf16(v2[0], 0.f);          //        (i8, pad)
      d[6] = cvt_pk_bf16(v2[1], v2[2]);        // l1=3: (i9,i10)
      d[7] = cvt_pk_bf16(v2[3], v3[0]);        //        (i11,i12)
      d[8] = cvt_pk_bf16(v3[1], v3[2]);        //        (i13,i14)
      d[9] = cvt_pk_bf16(v3[3], 0.f);          //        (i15, pad)
      #pragma unroll
      for (int ip = 0; ip < 10; ip++)
        x2s[ip*512 + el*32 + (c ^ sw)] = d[ip];
    }
  }

  f32x4 accm[4][2];
  #pragma unroll
  for (int q = 0; q < 4; q++){
    accm[q][0] = (f32x4){0.f,0.f,0.f,0.f};
    accm[q][1] = (f32x4){0.f,0.f,0.f,0.f};
  }

  __syncthreads();   // x2s / Yl2 / sdst visible

  const int lw = lane & 15;
  const int g  = lane >> 4;
  const int swr = xswz(lw);

  unsigned xs[8][4] = {};
  unsigned xsink = 0;

  auto pbody = [&](auto pc){
    constexpr int P   = (int)decltype(pc)::value;
    constexpr int L1v = PL1[P], L2v = PL2[P], L3v = PL3[P];
    constexpr int S1 = 2*L1v+1, S2 = 2*L2v+1, S3 = 2*L3v+1;
    constexpr int O2 = L2v*L2v, O3 = L3v*L3v;
    constexpr int S1p2 = (S1 + 1) / 2;
    constexpr int RS  = (L1v == 0) ? 2 : ((L1v == 1) ? 4 : 8);
    constexpr int CGF = PCGF[P];
    constexpr int PO  = PO1A[L1v];

    // ---- group head: x fragments LDS -> registers ----
    if constexpr (P == 0 || PL1[P] != PL1[P-1]){
      #pragma unroll
      for (int ip = 0; ip < S1p2; ip++){
        const int base = (PO + ip)*512 + lw*32;
        u32x4 xlo = *(const u32x4*)&x2s[base + ((8*g)     ^ swr)];
        u32x4 xhi = *(const u32x4*)&x2s[base + ((8*g + 4) ^ swr)];
        xs[0][ip] = xlo[0]; xs[1][ip] = xlo[1];
        xs[2][ip] = xlo[2]; xs[3][ip] = xlo[3];
        xs[4][ip] = xhi[0]; xs[5][ip] = xhi[1];
        xs[6][ip] = xhi[2]; xs[7][ip] = xhi[3];
      }
      if constexpr (V == 2){
        xsink = 0;
        #pragma unroll
        for (int ip = 0; ip < S1p2; ip++)
          #pragma unroll
          for (int q = 0; q < 8; q++) xsink ^= xs[q][ip];
      }
    }

    bool hasrow;
    if constexpr (S3 >= 4) hasrow = true;
    else hasrow = (((unsigned)(wv - O3) & 3u) < (unsigned)S3);
    if (!hasrow) return;

    // weight fragments (global, L2-hot)
    const short8 bw0 = *(const short8*)(wt + (size_t)(P*32 +      lw)*32 + g*8);
    const short8 bw1 = *(const short8*)(wt + (size_t)(P*32 + 16 + lw)*32 + g*8);

    #pragma unroll
    for (int kl = 0; kl < S3; kl++){
      if (((O3 + kl) & 3) == wv){          // wave-uniform branch
        // ---- B-comp: fully in-register, every lane computes its pairs ----
        unsigned bq[4] = {0u,0u,0u,0u};
        if constexpr (V != 1){
          f32x2 bacc[4];
          #pragma unroll
          for (int ip = 0; ip < S1p2; ip++) bacc[ip] = (f32x2){0.f,0.f};
          const float* cgrow = cgfg + CGF + kl*S2*RS;
          #pragma unroll
          for (int j = 0; j < S2; j++){
            f32x2 yj = Yl2[lw*17 + O2 + j];
            const float* cp = cgrow + j*RS;
            if constexpr (L1v == 0){
              bacc[0] = pk_fma(bacc[0], *(const f32x2*)cp, yj);
            } else if constexpr (L1v == 1){
              f32x4 cv = *(const f32x4*)cp;
              bacc[0] = pk_fma(bacc[0], __builtin_shufflevector(cv,cv,0,1), yj);
              bacc[1] = pk_fma(bacc[1], __builtin_shufflevector(cv,cv,2,3), yj);
            } else if constexpr (L1v == 2){
              f32x4 cv = *(const f32x4*)cp;
              f32x2 c2 = *(const f32x2*)(cp + 4);
              bacc[0] = pk_fma(bacc[0], __builtin_shufflevector(cv,cv,0,1), yj);
              bacc[1] = pk_fma(bacc[1], __builtin_shufflevector(cv,cv,2,3), yj);
              bacc[2] = pk_fma(bacc[2], c2, yj);
            } else {
              f32x4 cv = *(const f32x4*)cp;
              f32x4 cw = *(const f32x4*)(cp + 4);
              bacc[0] = pk_fma(bacc[0], __builtin_shufflevector(cv,cv,0,1), yj);
              bacc[1] = pk_fma(bacc[1], __builtin_shufflevector(cv,cv,2,3), yj);
              bacc[2] = pk_fma(bacc[2], __builtin_shufflevector(cw,cw,0,1), yj);
              bacc[3] = pk_fma(bacc[3], __builtin_shufflevector(cw,cw,2,3), yj);
            }
          }
          #pragma unroll
          for (int ip = 0; ip < S1p2; ip++)
            bq[ip] = cvt_pk_bf16(bacc[ip].x, bacc[ip].y);
        } else {
          #pragma unroll
          for (int ip = 0; ip < S1p2; ip++) bq[ip] = xs[ip][0];  // keep deps
        }
        // ---- a-comp: lane's own A-fragment (8 channels) via dot2 ----
        union { unsigned u[4]; short8 s; } afu;
        if constexpr (V != 2){
          float ac[8];
          #pragma unroll
          for (int q = 0; q < 8; q++) ac[q] = 0.f;
          #pragma unroll
          for (int ip = 0; ip < S1p2; ip++){
            #pragma unroll
            for (int q = 0; q < 8; q++)
              ac[q] = dot2bf(xs[q][ip], bq[ip], ac[q]);
          }
          afu.u[0] = cvt_pk_bf16(ac[0], ac[1]);
          afu.u[1] = cvt_pk_bf16(ac[2], ac[3]);
          afu.u[2] = cvt_pk_bf16(ac[4], ac[5]);
          afu.u[3] = cvt_pk_bf16(ac[6], ac[7]);
        } else {
          #pragma unroll
          for (int q = 0; q < 4; q++) afu.u[q] = bq[q] ^ xsink;  // keep live
        }
        // ---- MFMA ----
        const int ks = (O3 + kl) >> 2;
        accm[ks][0] = __builtin_amdgcn_mfma_f32_16x16x32_bf16(afu.s, bw0, accm[ks][0], 0, 0, 0);
        accm[ks][1] = __builtin_amdgcn_mfma_f32_16x16x32_bf16(afu.s, bw1, accm[ks][1], 0, 0, 0);
      }
    }
  };
  for_each_path(pbody, std::make_index_sequence<NPATH>{});

  __syncthreads();   // all x2s reads done before acc_l overlay

  // ---- epilogue: two half-tiles (kg 0..7 then 8..15), run-flush each ----
  #pragma unroll
  for (int half = 0; half < 2; half++){
    #pragma unroll
    for (int ks2 = 0; ks2 < 2; ks2++){
      const int ks = half*2 + ks2;
      const int kg = wv + 4*ks;
      #pragma unroll
      for (int dt2 = 0; dt2 < 2; dt2++){
        const int d = dt2*16 + lw;
        #pragma unroll
        for (int r = 0; r < 4; r++){
          const int e = 4*g + r;
          acc_l[(e*256 + (kg & 7)*32 + d) ^ (g << 3)] = accm[ks][dt2][r];
        }
      }
    }
    __syncthreads();
    {
      const int c = t;
      float v = 0.f; int prev = -2;
      #pragma unroll
      for (int s = 0; s < 16; s++){
        int dn = sdst[s];                        // block-uniform
        float av = acc_l[(s*256 + c) ^ (((s >> 2) & 3) << 3)];
        if (dn != prev){
          if (prev >= 0) unsafeAtomicAdd(accb + (size_t)prev*512 + half*256 + c, v);
          v = 0.f; prev = dn;
        }
        v += av;
      }
      if (prev >= 0) unsafeAtomicAdd(accb + (size_t)prev*512 + half*256 + c, v);
    }
    if (half == 0) __syncthreads();   // flush reads done before next writes
  }
}

// ------------------------------ linear kernel ------------------------------
__global__ __launch_bounds__(256, 4) void lin_kernel(
    const float* __restrict__ accb, const short* __restrict__ Wb,
    const float* __restrict__ bias, float* __restrict__ out, int N)
{
  __shared__ __align__(16) short As[64][32];
  __shared__ __align__(16) short Ws[64][32];
  const int t = threadIdx.x;
  const int lane = t & 63, wv = t >> 6;
  const int n0 = blockIdx.x * 64, o0 = blockIdx.y * 64;
  f32x4 acc4[4];
  #pragma unroll
  for (int q = 0; q < 4; q++) acc4[q] = (f32x4){0.f, 0.f, 0.f, 0.f};

  const int nn = t >> 2, kq = (t & 3) * 8;
  for (int kc = 0; kc < 16; kc++){
    __syncthreads();
    {
      short8 v8;
      int gn = n0 + nn;
      if (gn < N){
        const float* sp = accb + (size_t)gn*512 + kc*32 + kq;
        f32x4 f0 = ((const f32x4*)sp)[0], f1 = ((const f32x4*)sp)[1];
        v8[0] = f2bf(f0[0]); v8[1] = f2bf(f0[1]); v8[2] = f2bf(f0[2]); v8[3] = f2bf(f0[3]);
        v8[4] = f2bf(f1[0]); v8[5] = f2bf(f1[1]); v8[6] = f2bf(f1[2]); v8[7] = f2bf(f1[3]);
      } else {
        #pragma unroll
        for (int q = 0; q < 8; q++) v8[q] = 0;
      }
      *(short8*)&As[nn][kq] = v8;
      *(short8*)&Ws[nn][kq] = *(const short8*)(Wb + (size_t)(o0 + nn)*512 + kc*32 + kq);
    }
    __syncthreads();
    const short8 af = *(const short8*)&As[wv*16 + (lane & 15)][(lane >> 4) * 8];
    #pragma unroll
    for (int ct = 0; ct < 4; ct++){
      short8 bf8 = *(const short8*)&Ws[ct*16 + (lane & 15)][(lane >> 4) * 8];
      acc4[ct] = __builtin_amdgcn_mfma_f32_16x16x32_bf16(af, bf8, acc4[ct], 0, 0, 0);
    }
  }

  #pragma unroll
  for (int ct = 0; ct < 4; ct++){
    int o = o0 + ct*16 + (lane & 15);
    float bb = bias[o];
    #pragma unroll
    for (int r = 0; r < 4; r++){
      int n = n0 + wv*16 + (lane >> 4)*4 + r;
      if (n < N)
        out[(size_t)n*512 + o] = acc4[ct][r] + bb;
    }
  }
}

// ------------------------------ launcher -----------------------------------
extern "C" void kernel_launch(void* const* d_in, const int* in_sizes, int n_in,
                              void* d_out, int out_size, void* d_ws, size_t ws_size,
                              hipStream_t stream) {
  const float* nf  = (const float*)d_in[0];   // node_features (N,32,16) f32
  const int*   ei  = (const int*)d_in[1];     // edge_index (2,E) i32
  const float* ev  = (const float*)d_in[2];   // edge_vectors (E,3) f32
  const float* tpw = (const float*)d_in[3];   // tp_weights (34,32,32) f32
  const float* lw  = (const float*)d_in[4];   // linear_w (512,512) f32
  const float* lb  = (const float*)d_in[5];   // linear_b (512,) f32

  const int N = in_sizes[0] / 512;
  const int E = in_sizes[1] / 2;

  char* ws = (char*)d_ws;
  size_t off = 0;
  float* accb = (float*)(ws + off);
  off += (size_t)N * 512 * 4;          off = (off + 255) & ~(size_t)255;
  float* cgfg = (float*)(ws + off);
  off += (size_t)TOTCGF * 4;           off = (off + 255) & ~(size_t)255;
  short* wt   = (short*)(ws + off);
  off += (size_t)NPATH * 1024 * 2;     off = (off + 255) & ~(size_t)255;
  short* Wb   = (short*)(ws + off);
  off += (size_t)512 * 512 * 2;        off = (off + 255) & ~(size_t)255;
  int* cnt    = (int*)(ws + off);
  off += (size_t)N * 4;                off = (off + 255) & ~(size_t)255;
  int* perm   = (int*)(ws + off);
  off += (size_t)E * 4;
  if (off > ws_size) return;  // workspace too small: fail loudly via validation

  hipMemsetAsync(cnt, 0, (size_t)N * 4, stream);
  k_count<<<(E + 255) / 256, 256, 0, stream>>>(ei, cnt, E);
  k_scan<<<1, 256, 0, stream>>>(cnt, N);
  k_fill<<<(E + 255) / 256, 256, 0, stream>>>(ei, cnt, perm, E);
  prep_cgf<<<(TOTCGF + 255) / 256, 256, 0, stream>>>(cgfg);
  prep_w<<<(NPATH*1024 + 512*512 + 255) / 256, 256, 0, stream>>>(tpw, lw, wt, Wb);

  // DIAGNOSTIC dispatches (results wiped by the accb memset below):
  edge_kernel<1><<<(E + 15) / 16, 256, 0, stream>>>(nf, ei, ev, cgfg, wt, perm,
                                                    accb, E, N);
  edge_kernel<2><<<(E + 15) / 16, 256, 0, stream>>>(nf, ei, ev, cgfg, wt, perm,
                                                    accb, E, N);

  hipMemsetAsync(accb, 0, (size_t)N * 512 * 4, stream);
  edge_kernel<0><<<(E + 15) / 16, 256, 0, stream>>>(nf, ei, ev, cgfg, wt, perm,
                                                    accb, E, N);
  lin_kernel<<<dim3((N + 63) / 64, 8), 256, 0, stream>>>(accb, Wb, lb,
                                                         (float*)d_out, N);
}

// Round 8
// 463.773 us; speedup vs baseline: 1.7041x; 1.7041x over previous
//
#include <hip/hip_runtime.h>
#include <hip/hip_bf16.h>
#include <utility>

// ---------------------------------------------------------------------------
// BatteriesInteractionBlock: equivariant tensor-product message passing.
//   N=10000 nodes, E=160000 edges, C=32 channels, 16 irreps (L_MAX=3),
//   34 CG paths, scatter-sum over dst, then 512x512 linear. Output f32.
//
// Round-8 (from r7 ablation: B-comp marginal ~140us at 12x its MAC roofline,
// a-comp ~140us at ~70% of dot2 roofline, shared base ~60us):
//   - COOPERATIVE B-comp: per l1-group, 256 threads compute the whole
//     16-edge B-table in parallel into LDS (removes the 4x per-lane dup and
//     the serial cg-load->pk_fma->cvt critical chain). 2 barriers/group.
//   - a-comp reads B via one aligned b128/b64 LDS load per k-row.
//   - everything else kept: x2s swizzled staging, dot2 a-comp, MFMA,
//     dst-sorted edges, half-tile LDS flush epilogue (~38MB atomics).
// ---------------------------------------------------------------------------

#define NPATH 34
#define TOTCGF 4652

typedef __attribute__((ext_vector_type(2))) float f32x2;
typedef __attribute__((ext_vector_type(4))) float f32x4;
typedef __attribute__((ext_vector_type(2))) unsigned u32x2;
typedef __attribute__((ext_vector_type(4))) unsigned u32x4;
typedef __attribute__((ext_vector_type(8))) short short8;

// path tables: (l1,l2,l3) in reference order (sorted by l1)
constexpr int PL1[NPATH] = {0,0,0,0, 1,1,1,1,1,1,1,1,1, 2,2,2,2,2,2,2,2,2,2,2, 3,3,3,3,3,3,3,3,3,3};
constexpr int PL2[NPATH] = {0,1,2,3, 0,1,1,1,2,2,2,3,3, 0,1,1,1,2,2,2,2,3,3,3, 0,1,1,2,2,2,3,3,3,3};
constexpr int PL3[NPATH] = {0,1,2,3, 1,0,1,2,1,2,3,2,3, 2,1,2,3,0,1,2,3,1,2,3, 3,2,3,1,2,3,0,1,2,3};
// 16B-aligned cg starts; per-path row stride RS(l1) = {2,4,8,8}; layout
// [k][j][i(pad to RS)], slot = PCGF[p] + (k*S2 + j)*RS + i
constexpr int PCGF[NPATH] = {0,4,24,76, 176,188,200,236,296,356,456,596,736,
                             932,972,1044,1164,1332,1372,1492,1692,1972,2140,2420,
                             2812,2868,2988,3156,3276,3476,3756,3812,3980,4260};
// i-pair slot offsets per l1 block in x2s (widths {1,2,3,4}, 10 total)
constexpr int PO1A[4] = {0, 1, 3, 6};
// B-table: per-path base slot within its l1-group (pair-slot units);
// l1=2 paths padded to even so b64 stays aligned
constexpr int GB[NPATH] = {0,1,4,9,
                           0,6,8,14,24,30,40,54,64,
                           0,16,26,42,64,68,78,94,116,126,142,
                           0,28,48,76,88,108,136,140,152,172};
// per-l1-group edge stride in Bg (u32 units); gcd(stride,32)=4 -> 2-way banks
constexpr int GSTRIDE[4] = {20, 84, 164, 204};
constexpr int GSTART[5]  = {0, 4, 13, 24, 34};

__device__ __forceinline__ short f2bf(float f){
  unsigned u = __float_as_uint(f);
  unsigned r = (u + 0x7fffu + ((u >> 16) & 1u)) >> 16;
  return (short)r;
}

// ---- packed-math helpers (VOP3P asm verified on-device rounds 3-7) --------
__device__ __forceinline__ f32x2 pk_fma(f32x2 a, f32x2 x, f32x2 b){
  asm("v_pk_fma_f32 %0, %1, %2, %0" : "+v"(a) : "v"(x), "v"(b));
  return a;
}
__device__ __forceinline__ unsigned cvt_pk_bf16(float lo, float hi){
  unsigned r;
  asm("v_cvt_pk_bf16_f32 %0, %1, %2" : "=v"(r) : "v"(lo), "v"(hi));
  return r;
}
// c += a.lo*b.lo + a.hi*b.hi   (2x bf16 FMA, f32 accumulate)
__device__ __forceinline__ float dot2bf(unsigned a, unsigned b, float c){
  asm("v_dot2_f32_bf16 %0, %1, %2, %0" : "+v"(c) : "v"(a), "v"(b));
  return c;
}

// ------------------------------ prep_cgf -----------------------------------
__device__ double factd(int n){
  double f = 1.0;
  for (int i = 2; i <= n; i++) f *= (double)i;
  return f;
}

__device__ double cg_complex(int j1,int m1,int j2,int m2,int j3,int m3){
  if (m1 + m2 != m3) return 0.0;
  int dj = j1 - j2; if (dj < 0) dj = -dj;
  if (j3 < dj || j3 > j1 + j2) return 0.0;
  double pre = sqrt((double)(2*j3+1) * factd(j3+j1-j2) * factd(j3-j1+j2) *
                    factd(j1+j2-j3) / factd(j1+j2+j3+1));
  pre *= sqrt(factd(j3+m3)*factd(j3-m3)*factd(j1-m1)*factd(j1+m1)*
              factd(j2-m2)*factd(j2+m2));
  int k0 = 0;
  if (j2-j3-m1 > k0) k0 = j2-j3-m1;
  if (j1+m2-j3 > k0) k0 = j1+m2-j3;
  int k1 = j1+j2-j3;
  if (j1-m1 < k1) k1 = j1-m1;
  if (j2+m2 < k1) k1 = j2+m2;
  double s = 0.0;
  for (int k = k0; k <= k1; k++){
    double d = factd(k)*factd(j1+j2-j3-k)*factd(j1-m1-k)*factd(j2+m2-k)*
               factd(j3-j2+m1+k)*factd(j3-j1-m2+k);
    s += ((k & 1) ? -1.0 : 1.0) / d;
  }
  return pre * s;
}

struct Uent { int m; double re, im; };

__device__ int urow(int l, int a, Uent* o){
  const double s2 = 0.70710678118654752440;
  int ra = a - l;
  if (ra == 0){ o[0] = {0, 1.0, 0.0}; return 1; }
  if (ra > 0){
    int m = ra;
    o[0] = { -m, s2, 0.0 };
    o[1] = {  m, (m & 1) ? -s2 : s2, 0.0 };
    return 2;
  }
  int m = -ra;
  o[0] = { -m, 0.0, s2 };
  o[1] = {  m, 0.0, (m & 1) ? s2 : -s2 };
  return 2;
}

__device__ float real_cg(int l1, int l2, int l3, int i, int j, int k){
  Uent u1[2], u2[2], u3[2];
  int n1 = urow(l1, i, u1), n2 = urow(l2, j, u2), n3 = urow(l3, k, u3);
  double sre = 0.0, sim = 0.0;
  for (int a = 0; a < n1; a++)
    for (int b = 0; b < n2; b++)
      for (int c = 0; c < n3; c++){
        double cr = u1[a].re*u2[b].re - u1[a].im*u2[b].im;
        double ci = u1[a].re*u2[b].im + u1[a].im*u2[b].re;
        double tr = cr*u3[c].re + ci*u3[c].im;   // times conj(u3)
        double ti = ci*u3[c].re - cr*u3[c].im;
        double cgv = cg_complex(l1, u1[a].m, l2, u2[b].m, l3, u3[c].m);
        sre += tr*cgv; sim += ti*cgv;
      }
  return (float)((((l1+l2+l3) & 1) == 0) ? sre : sim);
}

__global__ void prep_cgf(float* __restrict__ cgf){
  int idx = blockIdx.x * blockDim.x + threadIdx.x;
  if (idx >= TOTCGF) return;
  int p = 0;
  for (int q = 1; q < NPATH; q++) if (idx >= PCGF[q]) p = q;
  const int l1 = PL1[p], l2 = PL2[p], l3 = PL3[p];
  const int S1 = 2*l1+1, S2 = 2*l2+1;
  const int RS = (l1 == 0) ? 2 : ((l1 == 1) ? 4 : 8);
  int q  = idx - PCGF[p];
  int kkj = q / RS;
  int ii  = q - kkj*RS;
  float v = 0.f;
  if (kkj < (2*l3+1)*S2 && ii < S1){
    int kk = kkj / S2;
    int j  = kkj - kk*S2;
    v = real_cg(l1, l2, l3, ii, j, kk);
  }
  cgf[idx] = v;
}

// ------------------------------ prep_w -------------------------------------
// wt[p][d][c] = bf16(tpw[p][c][d]);  Wb[o][ia] = bf16(W[o][(ia&31)*16 + (ia>>5)])
__global__ void prep_w(const float* __restrict__ tpw, const float* __restrict__ lw,
                       short* __restrict__ wt, short* __restrict__ Wb){
  int idx = blockIdx.x * blockDim.x + threadIdx.x;
  if (idx < NPATH*1024){
    int c = idx & 31, d = (idx >> 5) & 31, p = idx >> 10;
    wt[idx] = f2bf(tpw[(p << 10) + c*32 + d]);
  } else if (idx < NPATH*1024 + 512*512){
    int q = idx - NPATH*1024;
    int o = q >> 9, ia = q & 511;
    Wb[q] = f2bf(lw[o*512 + ((ia & 31) << 4) + (ia >> 5)]);
  }
}

// --------------------------- sort-by-dst prep ------------------------------
__global__ void k_count(const int* __restrict__ ei, int* __restrict__ cnt, int E){
  int e = blockIdx.x*256 + threadIdx.x;
  if (e < E) atomicAdd(&cnt[ei[E + e]], 1);
}

__global__ void k_scan(int* __restrict__ cnt, int N){
  __shared__ int part[256];
  const int t = threadIdx.x;
  const int base = t * 40;
  int loc[40];
  int s = 0;
  #pragma unroll
  for (int q = 0; q < 40; q++){
    int idx = base + q;
    int v = (idx < N) ? cnt[idx] : 0;
    loc[q] = s; s += v;
  }
  part[t] = s;
  __syncthreads();
  for (int d = 1; d < 256; d <<= 1){
    int v = (t >= d) ? part[t - d] : 0;
    __syncthreads();
    part[t] += v;
    __syncthreads();
  }
  int pre = (t == 0) ? 0 : part[t - 1];
  #pragma unroll
  for (int q = 0; q < 40; q++){
    int idx = base + q;
    if (idx < N) cnt[idx] = pre + loc[q];
  }
}

__global__ void k_fill(const int* __restrict__ ei, int* __restrict__ cur,
                       int* __restrict__ perm, int E){
  int e = blockIdx.x*256 + threadIdx.x;
  if (e < E){
    int pos = atomicAdd(&cur[ei[E + e]], 1);
    perm[pos] = e;
  }
}

// --------------------------- compile-time loops ----------------------------
template<int A, typename F, size_t... I>
__device__ __forceinline__ void for_range_impl(F&& f, std::index_sequence<I...>){
  (f(std::integral_constant<int, A + (int)I>{}), ...);
}
template<int A, int B, typename F>
__device__ __forceinline__ void for_range(F&& f){
  for_range_impl<A>(f, std::make_index_sequence<B - A>{});
}

// row swizzle for x2s: bits 2-4 of dword index, keeps b128 alignment
__device__ __forceinline__ int xswz(int r){
  return ((r & 3) << 2) | ((r & 1) << 4);
}

// ------------------------------ edge kernel --------------------------------
// 256 threads (4 waves), 16 dst-sorted edges/block. kg%4==wv wave split.
__global__ __launch_bounds__(256, 4) void edge_kernel(
    const float* __restrict__ nf, const int* __restrict__ ei,
    const float* __restrict__ ev, const float* __restrict__ cgfg,
    const short* __restrict__ wt, const int* __restrict__ perm,
    float* __restrict__ accb, int E, int N)
{
  // phase1: x2s[10][16][32] u32 [0,20480) + Ydup f32x2[16][17] [20480,22656)
  // phase2: acc_l[16][256] f32 [0,16384)   (time-disjoint overlay)
  __shared__ __align__(16) char u_lds[22656];
  unsigned* x2s   = (unsigned*)u_lds;
  f32x2*    Yl2   = (f32x2*)(u_lds + 20480);
  float*    acc_l = (float*)u_lds;
  __shared__ __align__(16) unsigned Bg[16*204];        // 13056 B B-table
  __shared__ int sdst[16];

  const int t    = threadIdx.x;
  const int lane = t & 63;
  const int wv   = t >> 6;
  const int e0   = blockIdx.x * 16;

  // ---- prologue: permuted edge meta + Y (first 16 threads) ----
  if (t < 16){
    int eg = e0 + t;
    int pe = (eg < E) ? perm[eg] : -1;
    float vx = 0.f, vy = 0.f, vz = 0.f; int dn = -1;
    if (pe >= 0){
      vx = ev[pe*3]; vy = ev[pe*3+1]; vz = ev[pe*3+2];
      dn = ei[E + pe];
    }
    float nrm = sqrtf(vx*vx + vy*vy + vz*vz);
    float inv = 1.0f / fmaxf(nrm, 1e-8f);
    float x = vx*inv, y = vy*inv, z = vz*inv;
    float x2 = x*x, y2 = y*y, z2 = z*z;
    float ys[16];
    ys[0]  = 0.28209479177387814f;
    ys[1]  = 0.4886025119029199f * y;
    ys[2]  = 0.4886025119029199f * z;
    ys[3]  = 0.4886025119029199f * x;
    ys[4]  = 1.0925484305920792f * x * y;
    ys[5]  = 1.0925484305920792f * y * z;
    ys[6]  = 0.31539156525252005f * (3.f*z2 - 1.f);
    ys[7]  = 1.0925484305920792f * x * z;
    ys[8]  = 0.5462742152960396f * (x2 - y2);
    ys[9]  = 0.5900435899266435f * y * (3.f*x2 - y2);
    ys[10] = 2.890611442640554f * x * y * z;
    ys[11] = 0.4570457994644658f * y * (5.f*z2 - 1.f);
    ys[12] = 0.3731763325901154f * z * (5.f*z2 - 3.f);
    ys[13] = 0.4570457994644658f * x * (5.f*z2 - 1.f);
    ys[14] = 1.445305721320277f * z * (x2 - y2);
    ys[15] = 0.5900435899266435f * x * (x2 - 3.f*y2);
    #pragma unroll
    for (int j = 0; j < 16; j++) Yl2[t*17 + j] = (f32x2){ys[j], ys[j]};
    sdst[t] = dn;
  }

  // ---- prologue: x gather (once, coalesced) -> packed bf16 pairs in x2s ----
  {
    const int el = t >> 4, c0 = t & 15;
    int eg = e0 + el;
    int pe = (eg < E) ? perm[eg] : -1;
    int s  = (pe >= 0) ? ei[pe] : 0;
    const float* xb = nf + (size_t)s * 512;
    const int sw = xswz(el);
    #pragma unroll
    for (int h = 0; h < 2; h++){
      const int c = c0 + 16*h;
      const float* rp = xb + c * 16;
      f32x4 v0 = ((const f32x4*)rp)[0];
      f32x4 v1 = ((const f32x4*)rp)[1];
      f32x4 v2 = ((const f32x4*)rp)[2];
      f32x4 v3 = ((const f32x4*)rp)[3];
      unsigned d[10];
      d[0] = cvt_pk_bf16(v0[0], 0.f);          // l1=0: (i0, pad)
      d[1] = cvt_pk_bf16(v0[1], v0[2]);        // l1=1: (i1,i2)
      d[2] = cvt_pk_bf16(v0[3], 0.f);          //        (i3, pad)
      d[3] = cvt_pk_bf16(v1[0], v1[1]);        // l1=2: (i4,i5)
      d[4] = cvt_pk_bf16(v1[2], v1[3]);        //        (i6,i7)
      d[5] = cvt_pk_bf16(v2[0], 0.f);          //        (i8, pad)
      d[6] = cvt_pk_bf16(v2[1], v2[2]);        // l1=3: (i9,i10)
      d[7] = cvt_pk_bf16(v2[3], v3[0]);        //        (i11,i12)
      d[8] = cvt_pk_bf16(v3[1], v3[2]);        //        (i13,i14)
      d[9] = cvt_pk_bf16(v3[3], 0.f);          //        (i15, pad)
      #pragma unroll
      for (int ip = 0; ip < 10; ip++)
        x2s[ip*512 + el*32 + (c ^ sw)] = d[ip];
    }
  }

  f32x4 accm[4][2];
  #pragma unroll
  for (int q = 0; q < 4; q++){
    accm[q][0] = (f32x4){0.f,0.f,0.f,0.f};
    accm[q][1] = (f32x4){0.f,0.f,0.f,0.f};
  }

  __syncthreads();   // x2s / Yl2 / sdst visible

  const int lw = lane & 15;
  const int g  = lane >> 4;
  const int swr = xswz(lw);

  unsigned xs[8][4] = {};

  // ================= main loop: 4 l1-groups ==============================
  auto gbody = [&](auto gc){
    constexpr int G    = (int)decltype(gc)::value;
    constexpr int L1v  = G;
    constexpr int S1   = 2*L1v + 1;
    constexpr int S1p2 = (S1 + 1) / 2;
    constexpr int RS   = (L1v == 0) ? 2 : ((L1v == 1) ? 4 : 8);
    constexpr int STR  = GSTRIDE[G];
    constexpr int PO   = PO1A[L1v];

    if constexpr (G > 0) __syncthreads();   // prev group's Bg reads done

    // ---- cooperative B-comp for all paths in group ----
    for_range<GSTART[G], GSTART[G+1]>([&](auto pc){
      constexpr int P  = (int)decltype(pc)::value;
      constexpr int S2 = 2*PL2[P] + 1, S3 = 2*PL3[P] + 1;
      constexpr int O2 = PL2[P]*PL2[P];
      constexpr int CGF = PCGF[P];
      constexpr int NIT = 16 * S3 * S1p2;
      for (int it = t; it < NIT; it += 256){
        int e  = it / (S3*S1p2);
        int rr = it - e*(S3*S1p2);
        int kl = rr / S1p2;
        int ip = rr - kl*S1p2;
        f32x2 bacc = {0.f, 0.f};
        const float* cgp = cgfg + CGF + kl*S2*RS + 2*ip;
        #pragma unroll
        for (int j = 0; j < S2; j++)
          bacc = pk_fma(bacc, *(const f32x2*)(cgp + j*RS), Yl2[e*17 + O2 + j]);
        Bg[e*STR + GB[P] + kl*S1p2 + ip] = cvt_pk_bf16(bacc.x, bacc.y);
      }
    });
    __syncthreads();   // Bg visible

    // ---- x fragments for this group: LDS -> registers ----
    #pragma unroll
    for (int ip = 0; ip < S1p2; ip++){
      const int base = (PO + ip)*512 + lw*32;
      u32x4 xlo = *(const u32x4*)&x2s[base + ((8*g)     ^ swr)];
      u32x4 xhi = *(const u32x4*)&x2s[base + ((8*g + 4) ^ swr)];
      xs[0][ip] = xlo[0]; xs[1][ip] = xlo[1];
      xs[2][ip] = xlo[2]; xs[3][ip] = xlo[3];
      xs[4][ip] = xhi[0]; xs[5][ip] = xhi[1];
      xs[6][ip] = xhi[2]; xs[7][ip] = xhi[3];
    }

    // ---- a-comp + MFMA per path ----
    for_range<GSTART[G], GSTART[G+1]>([&](auto pc){
      constexpr int P  = (int)decltype(pc)::value;
      constexpr int S3 = 2*PL3[P] + 1;
      constexpr int O3 = PL3[P]*PL3[P];

      bool hasrow;
      if constexpr (S3 >= 4) hasrow = true;
      else hasrow = (((unsigned)(wv - O3) & 3u) < (unsigned)S3);
      if (!hasrow) return;

      const short8 bw0 = *(const short8*)(wt + (size_t)(P*32 +      lw)*32 + g*8);
      const short8 bw1 = *(const short8*)(wt + (size_t)(P*32 + 16 + lw)*32 + g*8);

      #pragma unroll
      for (int kl = 0; kl < S3; kl++){
        if (((O3 + kl) & 3) == wv){        // wave-uniform
          // ---- B fragment from LDS (aligned by construction) ----
          unsigned bq[4];
          const int boff = lw*STR + GB[P] + kl*S1p2;
          if constexpr (S1p2 == 4){
            u32x4 b4 = *(const u32x4*)&Bg[boff];
            bq[0] = b4[0]; bq[1] = b4[1]; bq[2] = b4[2]; bq[3] = b4[3];
          } else if constexpr (S1p2 == 3){
            u32x2 b2 = *(const u32x2*)&Bg[boff & ~1];
            // boff parity varies with kl; load scalars to stay simple/safe
            bq[0] = Bg[boff]; bq[1] = Bg[boff+1]; bq[2] = Bg[boff+2];
            (void)b2;
          } else if constexpr (S1p2 == 2){
            u32x2 b2 = *(const u32x2*)&Bg[boff];
            bq[0] = b2[0]; bq[1] = b2[1];
          } else {
            bq[0] = Bg[boff];
          }
          // ---- a-comp: lane's own A-fragment (8 channels) via dot2 ----
          float ac[8];
          #pragma unroll
          for (int q = 0; q < 8; q++) ac[q] = 0.f;
          #pragma unroll
          for (int ip = 0; ip < S1p2; ip++){
            #pragma unroll
            for (int q = 0; q < 8; q++)
              ac[q] = dot2bf(xs[q][ip], bq[ip], ac[q]);
          }
          union { unsigned u[4]; short8 s; } afu;
          afu.u[0] = cvt_pk_bf16(ac[0], ac[1]);
          afu.u[1] = cvt_pk_bf16(ac[2], ac[3]);
          afu.u[2] = cvt_pk_bf16(ac[4], ac[5]);
          afu.u[3] = cvt_pk_bf16(ac[6], ac[7]);
          // ---- MFMA ----
          const int ks = (O3 + kl) >> 2;
          accm[ks][0] = __builtin_amdgcn_mfma_f32_16x16x32_bf16(afu.s, bw0, accm[ks][0], 0, 0, 0);
          accm[ks][1] = __builtin_amdgcn_mfma_f32_16x16x32_bf16(afu.s, bw1, accm[ks][1], 0, 0, 0);
        }
      }
    });
  };
  for_range<0, 4>(gbody);

  __syncthreads();   // all x2s/Bg reads done before acc_l overlay

  // ---- epilogue: two half-tiles (kg 0..7 then 8..15), run-flush each ----
  #pragma unroll
  for (int half = 0; half < 2; half++){
    #pragma unroll
    for (int ks2 = 0; ks2 < 2; ks2++){
      const int ks = half*2 + ks2;
      const int kg = wv + 4*ks;
      #pragma unroll
      for (int dt2 = 0; dt2 < 2; dt2++){
        const int d = dt2*16 + lw;
        #pragma unroll
        for (int r = 0; r < 4; r++){
          const int e = 4*g + r;
          acc_l[(e*256 + (kg & 7)*32 + d) ^ (g << 3)] = accm[ks][dt2][r];
        }
      }
    }
    __syncthreads();
    {
      const int c = t;
      float v = 0.f; int prev = -2;
      #pragma unroll
      for (int s = 0; s < 16; s++){
        int dn = sdst[s];                        // block-uniform
        float av = acc_l[(s*256 + c) ^ (((s >> 2) & 3) << 3)];
        if (dn != prev){
          if (prev >= 0) unsafeAtomicAdd(accb + (size_t)prev*512 + half*256 + c, v);
          v = 0.f; prev = dn;
        }
        v += av;
      }
      if (prev >= 0) unsafeAtomicAdd(accb + (size_t)prev*512 + half*256 + c, v);
    }
    if (half == 0) __syncthreads();   // flush reads done before next writes
  }
}

// ------------------------------ linear kernel ------------------------------
__global__ __launch_bounds__(256, 4) void lin_kernel(
    const float* __restrict__ accb, const short* __restrict__ Wb,
    const float* __restrict__ bias, float* __restrict__ out, int N)
{
  __shared__ __align__(16) short As[64][32];
  __shared__ __align__(16) short Ws[64][32];
  const int t = threadIdx.x;
  const int lane = t & 63, wv = t >> 6;
  const int n0 = blockIdx.x * 64, o0 = blockIdx.y * 64;
  f32x4 acc4[4];
  #pragma unroll
  for (int q = 0; q < 4; q++) acc4[q] = (f32x4){0.f, 0.f, 0.f, 0.f};

  const int nn = t >> 2, kq = (t & 3) * 8;
  for (int kc = 0; kc < 16; kc++){
    __syncthreads();
    {
      short8 v8;
      int gn = n0 + nn;
      if (gn < N){
        const float* sp = accb + (size_t)gn*512 + kc*32 + kq;
        f32x4 f0 = ((const f32x4*)sp)[0], f1 = ((const f32x4*)sp)[1];
        v8[0] = f2bf(f0[0]); v8[1] = f2bf(f0[1]); v8[2] = f2bf(f0[2]); v8[3] = f2bf(f0[3]);
        v8[4] = f2bf(f1[0]); v8[5] = f2bf(f1[1]); v8[6] = f2bf(f1[2]); v8[7] = f2bf(f1[3]);
      } else {
        #pragma unroll
        for (int q = 0; q < 8; q++) v8[q] = 0;
      }
      *(short8*)&As[nn][kq] = v8;
      *(short8*)&Ws[nn][kq] = *(const short8*)(Wb + (size_t)(o0 + nn)*512 + kc*32 + kq);
    }
    __syncthreads();
    const short8 af = *(const short8*)&As[wv*16 + (lane & 15)][(lane >> 4) * 8];
    #pragma unroll
    for (int ct = 0; ct < 4; ct++){
      short8 bf8 = *(const short8*)&Ws[ct*16 + (lane & 15)][(lane >> 4) * 8];
      acc4[ct] = __builtin_amdgcn_mfma_f32_16x16x32_bf16(af, bf8, acc4[ct], 0, 0, 0);
    }
  }

  #pragma unroll
  for (int ct = 0; ct < 4; ct++){
    int o = o0 + ct*16 + (lane & 15);
    float bb = bias[o];
    #pragma unroll
    for (int r = 0; r < 4; r++){
      int n = n0 + wv*16 + (lane >> 4)*4 + r;
      if (n < N)
        out[(size_t)n*512 + o] = acc4[ct][r] + bb;
    }
  }
}

// ------------------------------ launcher -----------------------------------
extern "C" void kernel_launch(void* const* d_in, const int* in_sizes, int n_in,
                              void* d_out, int out_size, void* d_ws, size_t ws_size,
                              hipStream_t stream) {
  const float* nf  = (const float*)d_in[0];   // node_features (N,32,16) f32
  const int*   ei  = (const int*)d_in[1];     // edge_index (2,E) i32
  const float* ev  = (const float*)d_in[2];   // edge_vectors (E,3) f32
  const float* tpw = (const float*)d_in[3];   // tp_weights (34,32,32) f32
  const float* lw  = (const float*)d_in[4];   // linear_w (512,512) f32
  const float* lb  = (const float*)d_in[5];   // linear_b (512,) f32

  const int N = in_sizes[0] / 512;
  const int E = in_sizes[1] / 2;

  char* ws = (char*)d_ws;
  size_t off = 0;
  float* accb = (float*)(ws + off);
  off += (size_t)N * 512 * 4;          off = (off + 255) & ~(size_t)255;
  float* cgfg = (float*)(ws + off);
  off += (size_t)TOTCGF * 4;           off = (off + 255) & ~(size_t)255;
  short* wt   = (short*)(ws + off);
  off += (size_t)NPATH * 1024 * 2;     off = (off + 255) & ~(size_t)255;
  short* Wb   = (short*)(ws + off);
  off += (size_t)512 * 512 * 2;        off = (off + 255) & ~(size_t)255;
  int* cnt    = (int*)(ws + off);
  off += (size_t)N * 4;                off = (off + 255) & ~(size_t)255;
  int* perm   = (int*)(ws + off);
  off += (size_t)E * 4;
  if (off > ws_size) return;  // workspace too small: fail loudly via validation

  hipMemsetAsync(accb, 0, (size_t)N * 512 * 4, stream);
  hipMemsetAsync(cnt, 0, (size_t)N * 4, stream);
  k_count<<<(E + 255) / 256, 256, 0, stream>>>(ei, cnt, E);
  k_scan<<<1, 256, 0, stream>>>(cnt, N);
  k_fill<<<(E + 255) / 256, 256, 0, stream>>>(ei, cnt, perm, E);
  prep_cgf<<<(TOTCGF + 255) / 256, 256, 0, stream>>>(cgfg);
  prep_w<<<(NPATH*1024 + 512*512 + 255) / 256, 256, 0, stream>>>(tpw, lw, wt, Wb);
  edge_kernel<<<(E + 15) / 16, 256, 0, stream>>>(nf, ei, ev, cgfg, wt, perm,
                                                 accb, E, N);
  lin_kernel<<<dim3((N + 63) / 64, 8), 256, 0, stream>>>(accb, Wb, lb,
                                                         (float*)d_out, N);
}

// Round 9
// 362.654 us; speedup vs baseline: 2.1792x; 1.2788x over previous
//
#include <hip/hip_runtime.h>
#include <hip/hip_bf16.h>
#include <utility>

// ---------------------------------------------------------------------------
// BatteriesInteractionBlock: equivariant tensor-product message passing.
//   N=10000 nodes, E=160000 edges, C=32 channels, 16 irreps (L_MAX=3),
//   34 CG paths, scatter-sum over dst, then 512x512 linear. Output f32.
//
// Round-9 (r7/r8 evidence: whole main loop runs at 3-4x hand-counted issue
// cost; cooperative+barriers regressed):
//   - wv = readfirstlane(t>>6): k-row ownership branches become SCALAR
//     (s_cmp/s_cbranch) instead of exec-masked regions. Same for flush dn.
//   - B-comp distributed across g-lanes (lane computes only its ip=g slot,
//     ds_bpermute broadcasts) -> true 4x issue cut, wave-local, no barriers.
//   - cg staged in LDS: inner-loop cg reads are imm-offset ds_read_b64
//     broadcasts (no 64b addressing, no vmcnt in the chain).
//   - keeps: x2s swizzled staging, dot2 a-comp, MFMA, dst-sorted edges,
//     half-tile LDS flush epilogue (~38MB atomics). LDS 39.4KB -> 4 blk/CU.
// ---------------------------------------------------------------------------

#define NPATH 34
#define TOTCGF 4174

typedef __attribute__((ext_vector_type(2))) float f32x2;
typedef __attribute__((ext_vector_type(4))) float f32x4;
typedef __attribute__((ext_vector_type(4))) unsigned u32x4;
typedef __attribute__((ext_vector_type(8))) short short8;

// path tables: (l1,l2,l3) in reference order (sorted by l1)
constexpr int PL1[NPATH] = {0,0,0,0, 1,1,1,1,1,1,1,1,1, 2,2,2,2,2,2,2,2,2,2,2, 3,3,3,3,3,3,3,3,3,3};
constexpr int PL2[NPATH] = {0,1,2,3, 0,1,1,1,2,2,2,3,3, 0,1,1,1,2,2,2,2,3,3,3, 0,1,1,2,2,2,3,3,3,3};
constexpr int PL3[NPATH] = {0,1,2,3, 1,0,1,2,1,2,3,2,3, 2,1,2,3,0,1,2,3,1,2,3, 3,2,3,1,2,3,0,1,2,3};
// pair-padded cg offsets: per path size S3*S2*(S1+1), layout [k][j][i(pad even)]
constexpr int PCGF[NPATH] = {0,2,20,70, 168,180,192,228,288,348,448,588,728,
                             924,954,1008,1098,1224,1254,1344,1494,1704,1830,2040,
                             2334,2390,2510,2678,2798,2998,3278,3334,3502,3782};
// i-pair slot offsets per l1 block in x2s (widths {1,2,3,4}, 10 total)
constexpr int PO1A[4] = {0, 1, 3, 6};

__device__ __forceinline__ short f2bf(float f){
  unsigned u = __float_as_uint(f);
  unsigned r = (u + 0x7fffu + ((u >> 16) & 1u)) >> 16;
  return (short)r;
}

// ---- packed-math helpers (VOP3P asm verified on-device rounds 3-8) --------
__device__ __forceinline__ f32x2 pk_fma(f32x2 a, f32x2 x, f32x2 b){
  asm("v_pk_fma_f32 %0, %1, %2, %0" : "+v"(a) : "v"(x), "v"(b));
  return a;
}
__device__ __forceinline__ unsigned cvt_pk_bf16(float lo, float hi){
  unsigned r;
  asm("v_cvt_pk_bf16_f32 %0, %1, %2" : "=v"(r) : "v"(lo), "v"(hi));
  return r;
}
// c += a.lo*b.lo + a.hi*b.hi   (2x bf16 FMA, f32 accumulate)
__device__ __forceinline__ float dot2bf(unsigned a, unsigned b, float c){
  asm("v_dot2_f32_bf16 %0, %1, %2, %0" : "+v"(c) : "v"(a), "v"(b));
  return c;
}

// ------------------------------ prep_cgf -----------------------------------
__device__ double factd(int n){
  double f = 1.0;
  for (int i = 2; i <= n; i++) f *= (double)i;
  return f;
}

__device__ double cg_complex(int j1,int m1,int j2,int m2,int j3,int m3){
  if (m1 + m2 != m3) return 0.0;
  int dj = j1 - j2; if (dj < 0) dj = -dj;
  if (j3 < dj || j3 > j1 + j2) return 0.0;
  double pre = sqrt((double)(2*j3+1) * factd(j3+j1-j2) * factd(j3-j1+j2) *
                    factd(j1+j2-j3) / factd(j1+j2+j3+1));
  pre *= sqrt(factd(j3+m3)*factd(j3-m3)*factd(j1-m1)*factd(j1+m1)*
              factd(j2-m2)*factd(j2+m2));
  int k0 = 0;
  if (j2-j3-m1 > k0) k0 = j2-j3-m1;
  if (j1+m2-j3 > k0) k0 = j1+m2-j3;
  int k1 = j1+j2-j3;
  if (j1-m1 < k1) k1 = j1-m1;
  if (j2+m2 < k1) k1 = j2+m2;
  double s = 0.0;
  for (int k = k0; k <= k1; k++){
    double d = factd(k)*factd(j1+j2-j3-k)*factd(j1-m1-k)*factd(j2+m2-k)*
               factd(j3-j2+m1+k)*factd(j3-j1-m2+k);
    s += ((k & 1) ? -1.0 : 1.0) / d;
  }
  return pre * s;
}

struct Uent { int m; double re, im; };

__device__ int urow(int l, int a, Uent* o){
  const double s2 = 0.70710678118654752440;
  int ra = a - l;
  if (ra == 0){ o[0] = {0, 1.0, 0.0}; return 1; }
  if (ra > 0){
    int m = ra;
    o[0] = { -m, s2, 0.0 };
    o[1] = {  m, (m & 1) ? -s2 : s2, 0.0 };
    return 2;
  }
  int m = -ra;
  o[0] = { -m, 0.0, s2 };
  o[1] = {  m, 0.0, (m & 1) ? s2 : -s2 };
  return 2;
}

__device__ float real_cg(int l1, int l2, int l3, int i, int j, int k){
  Uent u1[2], u2[2], u3[2];
  int n1 = urow(l1, i, u1), n2 = urow(l2, j, u2), n3 = urow(l3, k, u3);
  double sre = 0.0, sim = 0.0;
  for (int a = 0; a < n1; a++)
    for (int b = 0; b < n2; b++)
      for (int c = 0; c < n3; c++){
        double cr = u1[a].re*u2[b].re - u1[a].im*u2[b].im;
        double ci = u1[a].re*u2[b].im + u1[a].im*u2[b].re;
        double tr = cr*u3[c].re + ci*u3[c].im;   // times conj(u3)
        double ti = ci*u3[c].re - cr*u3[c].im;
        double cgv = cg_complex(l1, u1[a].m, l2, u2[b].m, l3, u3[c].m);
        sre += tr*cgv; sim += ti*cgv;
      }
  return (float)((((l1+l2+l3) & 1) == 0) ? sre : sim);
}

// writes cgf[slot] with slot = PCGF[p] + (k*S2 + j)*(S1+1) + i  (i pad -> 0)
__global__ void prep_cgf(float* __restrict__ cgf){
  int idx = blockIdx.x * blockDim.x + threadIdx.x;
  if (idx >= TOTCGF) return;
  int p = 0;
  for (int q = 1; q < NPATH; q++) if (idx >= PCGF[q]) p = q;
  const int l1 = PL1[p], l2 = PL2[p], l3 = PL3[p];
  const int S1 = 2*l1+1, S2 = 2*l2+1, S1p = S1+1;
  int q  = idx - PCGF[p];
  int kkj = q / S1p;
  int ii  = q - kkj*S1p;
  float v = 0.f;
  if (ii < S1){
    int kk = kkj / S2;
    int j  = kkj - kk*S2;
    v = real_cg(l1, l2, l3, ii, j, kk);
  }
  cgf[idx] = v;
}

// ------------------------------ prep_w -------------------------------------
// wt[p][d][c] = bf16(tpw[p][c][d]);  Wb[o][ia] = bf16(W[o][(ia&31)*16 + (ia>>5)])
__global__ void prep_w(const float* __restrict__ tpw, const float* __restrict__ lw,
                       short* __restrict__ wt, short* __restrict__ Wb){
  int idx = blockIdx.x * blockDim.x + threadIdx.x;
  if (idx < NPATH*1024){
    int c = idx & 31, d = (idx >> 5) & 31, p = idx >> 10;
    wt[idx] = f2bf(tpw[(p << 10) + c*32 + d]);
  } else if (idx < NPATH*1024 + 512*512){
    int q = idx - NPATH*1024;
    int o = q >> 9, ia = q & 511;
    Wb[q] = f2bf(lw[o*512 + ((ia & 31) << 4) + (ia >> 5)]);
  }
}

// --------------------------- sort-by-dst prep ------------------------------
__global__ void k_count(const int* __restrict__ ei, int* __restrict__ cnt, int E){
  int e = blockIdx.x*256 + threadIdx.x;
  if (e < E) atomicAdd(&cnt[ei[E + e]], 1);
}

__global__ void k_scan(int* __restrict__ cnt, int N){
  __shared__ int part[256];
  const int t = threadIdx.x;
  const int base = t * 40;
  int loc[40];
  int s = 0;
  #pragma unroll
  for (int q = 0; q < 40; q++){
    int idx = base + q;
    int v = (idx < N) ? cnt[idx] : 0;
    loc[q] = s; s += v;
  }
  part[t] = s;
  __syncthreads();
  for (int d = 1; d < 256; d <<= 1){
    int v = (t >= d) ? part[t - d] : 0;
    __syncthreads();
    part[t] += v;
    __syncthreads();
  }
  int pre = (t == 0) ? 0 : part[t - 1];
  #pragma unroll
  for (int q = 0; q < 40; q++){
    int idx = base + q;
    if (idx < N) cnt[idx] = pre + loc[q];
  }
}

__global__ void k_fill(const int* __restrict__ ei, int* __restrict__ cur,
                       int* __restrict__ perm, int E){
  int e = blockIdx.x*256 + threadIdx.x;
  if (e < E){
    int pos = atomicAdd(&cur[ei[E + e]], 1);
    perm[pos] = e;
  }
}

// --------------------------- path expansion helper -------------------------
template<typename F, size_t... I>
__device__ __forceinline__ void for_each_path(F&& f, std::index_sequence<I...>){
  (f(std::integral_constant<size_t, I>{}), ...);
}

// row swizzle for x2s: bits 2-4 of dword index, keeps b128 alignment
__device__ __forceinline__ int xswz(int r){
  return ((r & 3) << 2) | ((r & 1) << 4);
}

// ------------------------------ edge kernel --------------------------------
// 256 threads (4 waves), 16 dst-sorted edges/block. kg%4==wv wave split
// (wv scalarized). Lane role: lw = lane&15 (edge), g = lane>>4 (ch chunk).
__global__ __launch_bounds__(256, 4) void edge_kernel(
    const float* __restrict__ nf, const int* __restrict__ ei,
    const float* __restrict__ ev, const float* __restrict__ cgfg,
    const short* __restrict__ wt, const int* __restrict__ perm,
    float* __restrict__ accb, int E, int N)
{
  // phase1: x2s[10][16][32] u32 [0,20480) + Ydup f32x2[16][17] [20480,22656)
  // phase2: acc_l[16][256] f32 [0,16384)   (time-disjoint overlay of x2s)
  __shared__ __align__(16) char u_lds[22656];
  unsigned* x2s   = (unsigned*)u_lds;
  f32x2*    Yl2   = (f32x2*)(u_lds + 20480);
  float*    acc_l = (float*)u_lds;
  __shared__ __align__(16) float cgl[TOTCGF];          // 16696 B
  __shared__ int sdst[16];

  const int t    = threadIdx.x;
  const int lane = t & 63;
  const int wv   = __builtin_amdgcn_readfirstlane(t >> 6);  // SCALAR wave id
  const int e0   = blockIdx.x * 16;

  // ---- prologue: stage cg table into LDS (17 coalesced loads/thread) ----
  for (int i = t; i < TOTCGF; i += 256) cgl[i] = cgfg[i];

  // ---- prologue: permuted edge meta + Y (first 16 threads) ----
  if (t < 16){
    int eg = e0 + t;
    int pe = (eg < E) ? perm[eg] : -1;
    float vx = 0.f, vy = 0.f, vz = 0.f; int dn = -1;
    if (pe >= 0){
      vx = ev[pe*3]; vy = ev[pe*3+1]; vz = ev[pe*3+2];
      dn = ei[E + pe];
    }
    float nrm = sqrtf(vx*vx + vy*vy + vz*vz);
    float inv = 1.0f / fmaxf(nrm, 1e-8f);
    float x = vx*inv, y = vy*inv, z = vz*inv;
    float x2 = x*x, y2 = y*y, z2 = z*z;
    float ys[16];
    ys[0]  = 0.28209479177387814f;
    ys[1]  = 0.4886025119029199f * y;
    ys[2]  = 0.4886025119029199f * z;
    ys[3]  = 0.4886025119029199f * x;
    ys[4]  = 1.0925484305920792f * x * y;
    ys[5]  = 1.0925484305920792f * y * z;
    ys[6]  = 0.31539156525252005f * (3.f*z2 - 1.f);
    ys[7]  = 1.0925484305920792f * x * z;
    ys[8]  = 0.5462742152960396f * (x2 - y2);
    ys[9]  = 0.5900435899266435f * y * (3.f*x2 - y2);
    ys[10] = 2.890611442640554f * x * y * z;
    ys[11] = 0.4570457994644658f * y * (5.f*z2 - 1.f);
    ys[12] = 0.3731763325901154f * z * (5.f*z2 - 3.f);
    ys[13] = 0.4570457994644658f * x * (5.f*z2 - 1.f);
    ys[14] = 1.445305721320277f * z * (x2 - y2);
    ys[15] = 0.5900435899266435f * x * (x2 - 3.f*y2);
    #pragma unroll
    for (int j = 0; j < 16; j++) Yl2[t*17 + j] = (f32x2){ys[j], ys[j]};
    sdst[t] = dn;
  }

  // ---- prologue: x gather (once, coalesced) -> packed bf16 pairs in x2s ----
  {
    const int el = t >> 4, c0 = t & 15;
    int eg = e0 + el;
    int pe = (eg < E) ? perm[eg] : -1;
    int s  = (pe >= 0) ? ei[pe] : 0;
    const float* xb = nf + (size_t)s * 512;
    const int sw = xswz(el);
    #pragma unroll
    for (int h = 0; h < 2; h++){
      const int c = c0 + 16*h;
      const float* rp = xb + c * 16;
      f32x4 v0 = ((const f32x4*)rp)[0];
      f32x4 v1 = ((const f32x4*)rp)[1];
      f32x4 v2 = ((const f32x4*)rp)[2];
      f32x4 v3 = ((const f32x4*)rp)[3];
      unsigned d[10];
      d[0] = cvt_pk_bf16(v0[0], 0.f);          // l1=0: (i0, pad)
      d[1] = cvt_pk_bf16(v0[1], v0[2]);        // l1=1: (i1,i2)
      d[2] = cvt_pk_bf16(v0[3], 0.f);          //        (i3, pad)
      d[3] = cvt_pk_bf16(v1[0], v1[1]);        // l1=2: (i4,i5)
      d[4] = cvt_pk_bf16(v1[2], v1[3]);        //        (i6,i7)
      d[5] = cvt_pk_bf16(v2[0], 0.f);          //        (i8, pad)
      d[6] = cvt_pk_bf16(v2[1], v2[2]);        // l1=3: (i9,i10)
      d[7] = cvt_pk_bf16(v2[3], v3[0]);        //        (i11,i12)
      d[8] = cvt_pk_bf16(v3[1], v3[2]);        //        (i13,i14)
      d[9] = cvt_pk_bf16(v3[3], 0.f);          //        (i15, pad)
      #pragma unroll
      for (int ip = 0; ip < 10; ip++)
        x2s[ip*512 + el*32 + (c ^ sw)] = d[ip];
    }
  }

  f32x4 accm[4][2];
  #pragma unroll
  for (int q = 0; q < 4; q++){
    accm[q][0] = (f32x4){0.f,0.f,0.f,0.f};
    accm[q][1] = (f32x4){0.f,0.f,0.f,0.f};
  }

  __syncthreads();   // cgl / x2s / Yl2 / sdst visible

  const int lw   = lane & 15;
  const int g    = lane >> 4;
  const int swr  = xswz(lw);
  const int lwx4 = lw * 4;          // bpermute byte index base

  unsigned xs[8][4] = {};

  auto pbody = [&](auto pc){
    constexpr int P   = (int)decltype(pc)::value;
    constexpr int L1v = PL1[P], L2v = PL2[P], L3v = PL3[P];
    constexpr int S1 = 2*L1v+1, S2 = 2*L2v+1, S3 = 2*L3v+1;
    constexpr int O2 = L2v*L2v, O3 = L3v*L3v;
    constexpr int S1p  = S1 + 1;
    constexpr int S1p2 = S1p / 2;
    constexpr int CGF  = PCGF[P];
    constexpr int PO   = PO1A[L1v];

    // ---- group head: x fragments LDS -> registers ----
    if constexpr (P == 0 || PL1[P] != PL1[P-1]){
      #pragma unroll
      for (int ip = 0; ip < S1p2; ip++){
        const int base = (PO + ip)*512 + lw*32;
        u32x4 xlo = *(const u32x4*)&x2s[base + ((8*g)     ^ swr)];
        u32x4 xhi = *(const u32x4*)&x2s[base + ((8*g + 4) ^ swr)];
        xs[0][ip] = xlo[0]; xs[1][ip] = xlo[1];
        xs[2][ip] = xlo[2]; xs[3][ip] = xlo[3];
        xs[4][ip] = xhi[0]; xs[5][ip] = xhi[1];
        xs[6][ip] = xhi[2]; xs[7][ip] = xhi[3];
      }
    }

    // wave participates? (wv is SGPR -> scalar branch)
    bool hasrow;
    if constexpr (S3 >= 4) hasrow = true;
    else hasrow = (((unsigned)(wv - O3) & 3u) < (unsigned)S3);
    if (!hasrow) return;

    // weight fragments (global, L2-hot)
    const short8 bw0 = *(const short8*)(wt + (size_t)(P*32 +      lw)*32 + g*8);
    const short8 bw1 = *(const short8*)(wt + (size_t)(P*32 + 16 + lw)*32 + g*8);

    #pragma unroll
    for (int kl = 0; kl < S3; kl++){
      if (((O3 + kl) & 3) == wv){        // SCALAR compare -> s_cbranch
        // ---- B-comp: lane g computes ONLY pair-slot ip=g (1x issue) ----
        unsigned bq_own = 0;
        if (g < S1p2){
          f32x2 bacc = {0.f, 0.f};
          #pragma unroll
          for (int j = 0; j < S2; j++)
            bacc = pk_fma(bacc,
                          *(const f32x2*)&cgl[CGF + (kl*S2 + j)*S1p + 2*g],
                          Yl2[lw*17 + O2 + j]);
          bq_own = cvt_pk_bf16(bacc.x, bacc.y);
        }
        // broadcast the S1p2 slots wave-locally (src lane = lw + 16*ip)
        unsigned bq[4];
        #pragma unroll
        for (int ip = 0; ip < S1p2; ip++)
          bq[ip] = (unsigned)__builtin_amdgcn_ds_bpermute(lwx4 + 64*ip,
                                                          (int)bq_own);
        // ---- a-comp: lane's own A-fragment (8 channels) via dot2 ----
        float ac[8];
        #pragma unroll
        for (int q = 0; q < 8; q++) ac[q] = 0.f;
        #pragma unroll
        for (int ip = 0; ip < S1p2; ip++){
          #pragma unroll
          for (int q = 0; q < 8; q++)
            ac[q] = dot2bf(xs[q][ip], bq[ip], ac[q]);
        }
        union { unsigned u[4]; short8 s; } afu;
        afu.u[0] = cvt_pk_bf16(ac[0], ac[1]);
        afu.u[1] = cvt_pk_bf16(ac[2], ac[3]);
        afu.u[2] = cvt_pk_bf16(ac[4], ac[5]);
        afu.u[3] = cvt_pk_bf16(ac[6], ac[7]);
        // ---- MFMA: C[e][d] += a[e][c] * w[c][d], d-halves 0/1 ----
        const int ks = (O3 + kl) >> 2;
        accm[ks][0] = __builtin_amdgcn_mfma_f32_16x16x32_bf16(afu.s, bw0, accm[ks][0], 0, 0, 0);
        accm[ks][1] = __builtin_amdgcn_mfma_f32_16x16x32_bf16(afu.s, bw1, accm[ks][1], 0, 0, 0);
      }
    }
  };
  for_each_path(pbody, std::make_index_sequence<NPATH>{});

  __syncthreads();   // all x2s reads done before acc_l overlay

  // ---- epilogue: two half-tiles (kg 0..7 then 8..15), run-flush each ----
  #pragma unroll
  for (int half = 0; half < 2; half++){
    #pragma unroll
    for (int ks2 = 0; ks2 < 2; ks2++){
      const int ks = half*2 + ks2;
      const int kg = wv + 4*ks;
      #pragma unroll
      for (int dt2 = 0; dt2 < 2; dt2++){
        const int d = dt2*16 + lw;
        #pragma unroll
        for (int r = 0; r < 4; r++){
          const int e = 4*g + r;
          acc_l[(e*256 + (kg & 7)*32 + d) ^ (g << 3)] = accm[ks][dt2][r];
        }
      }
    }
    __syncthreads();
    {
      const int c = t;
      float v = 0.f; int prev = -2;
      #pragma unroll
      for (int s = 0; s < 16; s++){
        int dn = __builtin_amdgcn_readfirstlane(sdst[s]);  // block-uniform
        float av = acc_l[(s*256 + c) ^ (((s >> 2) & 3) << 3)];
        if (dn != prev){
          if (prev >= 0) unsafeAtomicAdd(accb + (size_t)prev*512 + half*256 + c, v);
          v = 0.f; prev = dn;
        }
        v += av;
      }
      if (prev >= 0) unsafeAtomicAdd(accb + (size_t)prev*512 + half*256 + c, v);
    }
    if (half == 0) __syncthreads();   // flush reads done before next writes
  }
}

// ------------------------------ linear kernel ------------------------------
__global__ __launch_bounds__(256, 4) void lin_kernel(
    const float* __restrict__ accb, const short* __restrict__ Wb,
    const float* __restrict__ bias, float* __restrict__ out, int N)
{
  __shared__ __align__(16) short As[64][32];
  __shared__ __align__(16) short Ws[64][32];
  const int t = threadIdx.x;
  const int lane = t & 63, wv = t >> 6;
  const int n0 = blockIdx.x * 64, o0 = blockIdx.y * 64;
  f32x4 acc4[4];
  #pragma unroll
  for (int q = 0; q < 4; q++) acc4[q] = (f32x4){0.f, 0.f, 0.f, 0.f};

  const int nn = t >> 2, kq = (t & 3) * 8;
  for (int kc = 0; kc < 16; kc++){
    __syncthreads();
    {
      short8 v8;
      int gn = n0 + nn;
      if (gn < N){
        const float* sp = accb + (size_t)gn*512 + kc*32 + kq;
        f32x4 f0 = ((const f32x4*)sp)[0], f1 = ((const f32x4*)sp)[1];
        v8[0] = f2bf(f0[0]); v8[1] = f2bf(f0[1]); v8[2] = f2bf(f0[2]); v8[3] = f2bf(f0[3]);
        v8[4] = f2bf(f1[0]); v8[5] = f2bf(f1[1]); v8[6] = f2bf(f1[2]); v8[7] = f2bf(f1[3]);
      } else {
        #pragma unroll
        for (int q = 0; q < 8; q++) v8[q] = 0;
      }
      *(short8*)&As[nn][kq] = v8;
      *(short8*)&Ws[nn][kq] = *(const short8*)(Wb + (size_t)(o0 + nn)*512 + kc*32 + kq);
    }
    __syncthreads();
    const short8 af = *(const short8*)&As[wv*16 + (lane & 15)][(lane >> 4) * 8];
    #pragma unroll
    for (int ct = 0; ct < 4; ct++){
      short8 bf8 = *(const short8*)&Ws[ct*16 + (lane & 15)][(lane >> 4) * 8];
      acc4[ct] = __builtin_amdgcn_mfma_f32_16x16x32_bf16(af, bf8, acc4[ct], 0, 0, 0);
    }
  }

  #pragma unroll
  for (int ct = 0; ct < 4; ct++){
    int o = o0 + ct*16 + (lane & 15);
    float bb = bias[o];
    #pragma unroll
    for (int r = 0; r < 4; r++){
      int n = n0 + wv*16 + (lane >> 4)*4 + r;
      if (n < N)
        out[(size_t)n*512 + o] = acc4[ct][r] + bb;
    }
  }
}

// ------------------------------ launcher -----------------------------------
extern "C" void kernel_launch(void* const* d_in, const int* in_sizes, int n_in,
                              void* d_out, int out_size, void* d_ws, size_t ws_size,
                              hipStream_t stream) {
  const float* nf  = (const float*)d_in[0];   // node_features (N,32,16) f32
  const int*   ei  = (const int*)d_in[1];     // edge_index (2,E) i32
  const float* ev  = (const float*)d_in[2];   // edge_vectors (E,3) f32
  const float* tpw = (const float*)d_in[3];   // tp_weights (34,32,32) f32
  const float* lw  = (const float*)d_in[4];   // linear_w (512,512) f32
  const float* lb  = (const float*)d_in[5];   // linear_b (512,) f32

  const int N = in_sizes[0] / 512;
  const int E = in_sizes[1] / 2;

  char* ws = (char*)d_ws;
  size_t off = 0;
  float* accb = (float*)(ws + off);
  off += (size_t)N * 512 * 4;          off = (off + 255) & ~(size_t)255;
  float* cgfg = (float*)(ws + off);
  off += (size_t)TOTCGF * 4;           off = (off + 255) & ~(size_t)255;
  short* wt   = (short*)(ws + off);
  off += (size_t)NPATH * 1024 * 2;     off = (off + 255) & ~(size_t)255;
  short* Wb   = (short*)(ws + off);
  off += (size_t)512 * 512 * 2;        off = (off + 255) & ~(size_t)255;
  int* cnt    = (int*)(ws + off);
  off += (size_t)N * 4;                off = (off + 255) & ~(size_t)255;
  int* perm   = (int*)(ws + off);
  off += (size_t)E * 4;
  if (off > ws_size) return;  // workspace too small: fail loudly via validation

  hipMemsetAsync(accb, 0, (size_t)N * 512 * 4, stream);
  hipMemsetAsync(cnt, 0, (size_t)N * 4, stream);
  k_count<<<(E + 255) / 256, 256, 0, stream>>>(ei, cnt, E);
  k_scan<<<1, 256, 0, stream>>>(cnt, N);
  k_fill<<<(E + 255) / 256, 256, 0, stream>>>(ei, cnt, perm, E);
  prep_cgf<<<(TOTCGF + 255) / 256, 256, 0, stream>>>(cgfg);
  prep_w<<<(NPATH*1024 + 512*512 + 255) / 256, 256, 0, stream>>>(tpw, lw, wt, Wb);
  edge_kernel<<<(E + 15) / 16, 256, 0, stream>>>(nf, ei, ev, cgfg, wt, perm,
                                                 accb, E, N);
  lin_kernel<<<dim3((N + 63) / 64, 8), 256, 0, stream>>>(accb, Wb, lb,
                                                         (float*)d_out, N);
}